// Round 1
// baseline (2451.398 us; speedup 1.0000x reference)
//
#include <hip/hip_runtime.h>

#define T_STEPS 250
#define BATCH   256
#define IN_DIM  700
#define HID     1024
#define W_LD    1724   // = IN_DIM + HID
#define OUT_DIM 20

// ---------------------------------------------------------------------------
// Transpose recurrent weights: WhhT[j][h] = W_h[h][700 + j]
// ---------------------------------------------------------------------------
__global__ __launch_bounds__(256)
void transpose_whh(const float* __restrict__ W_h, float* __restrict__ WhhT) {
    __shared__ float tile[32][33];
    const int bx = blockIdx.x * 32;  // h base
    const int by = blockIdx.y * 32;  // j base
    const int tx = threadIdx.x, ty = threadIdx.y;
#pragma unroll
    for (int i = 0; i < 32; i += 8) {
        const int h = bx + ty + i;
        const int j = by + tx;
        tile[ty + i][tx] = W_h[(size_t)h * W_LD + IN_DIM + j];
    }
    __syncthreads();
#pragma unroll
    for (int i = 0; i < 32; i += 8) {
        const int j = by + ty + i;
        const int h = bx + tx;
        WhhT[(size_t)j * HID + h] = tile[tx][ty + i];
    }
}

// ---------------------------------------------------------------------------
// Input-current GEMM: C[m][n] = sum_k X[m][k] * W[n][k],  K = 700 (cols 0..699
// of W_h, ld = 1724). 128x128 tile, 256 threads, 8x8 per thread, fp32 VALU.
// ---------------------------------------------------------------------------
#define BM 128
#define BN 128
#define BKK 16
#define LDP (BM + 4)

__global__ __launch_bounds__(256)
void input_gemm(const float* __restrict__ X, const float* __restrict__ W,
                float* __restrict__ C, int M) {
    (void)M;
    __shared__ float As[BKK][LDP];
    __shared__ float Bs[BKK][LDP];
    const int tid = threadIdx.x;
    const int bm = blockIdx.x * BM;
    const int bn = blockIdx.y * BN;
    const int r0 = (tid >> 4) * 8;
    const int c0 = (tid & 15) * 8;

    float4 aReg[2], bReg[2];

    auto stage = [&](int k0) {
#pragma unroll
        for (int r = 0; r < 2; ++r) {
            const int idx = r * 256 + tid;
            const int row = idx >> 2;
            const int k   = k0 + (idx & 3) * 4;
            {
                const float* p = X + (size_t)(bm + row) * IN_DIM + k;
                float4 v = make_float4(0.f, 0.f, 0.f, 0.f);
                if (k + 3 < IN_DIM) v = *(const float4*)p;
                else if (k < IN_DIM) {
                    v.x = p[0];
                    if (k + 1 < IN_DIM) v.y = p[1];
                    if (k + 2 < IN_DIM) v.z = p[2];
                }
                aReg[r] = v;
            }
            {
                const float* p = W + (size_t)(bn + row) * W_LD + k;
                float4 v = make_float4(0.f, 0.f, 0.f, 0.f);
                if (k + 3 < IN_DIM) v = *(const float4*)p;
                else if (k < IN_DIM) {
                    v.x = p[0];
                    if (k + 1 < IN_DIM) v.y = p[1];
                    if (k + 2 < IN_DIM) v.z = p[2];
                }
                bReg[r] = v;
            }
        }
    };
    auto commit = [&]() {
#pragma unroll
        for (int r = 0; r < 2; ++r) {
            const int idx = r * 256 + tid;
            const int row = idx >> 2;
            const int kk  = (idx & 3) * 4;
            As[kk + 0][row] = aReg[r].x;
            As[kk + 1][row] = aReg[r].y;
            As[kk + 2][row] = aReg[r].z;
            As[kk + 3][row] = aReg[r].w;
            Bs[kk + 0][row] = bReg[r].x;
            Bs[kk + 1][row] = bReg[r].y;
            Bs[kk + 2][row] = bReg[r].z;
            Bs[kk + 3][row] = bReg[r].w;
        }
    };

    float acc[8][8];
#pragma unroll
    for (int i = 0; i < 8; ++i)
#pragma unroll
        for (int j = 0; j < 8; ++j) acc[i][j] = 0.f;

    const int nk = (IN_DIM + BKK - 1) / BKK;  // 44
    stage(0);
    for (int kt = 0; kt < nk; ++kt) {
        commit();
        __syncthreads();
        if (kt + 1 < nk) stage((kt + 1) * BKK);
#pragma unroll
        for (int kk = 0; kk < BKK; ++kk) {
            float a[8], b[8];
            *(float4*)&a[0] = *(const float4*)&As[kk][r0];
            *(float4*)&a[4] = *(const float4*)&As[kk][r0 + 4];
            *(float4*)&b[0] = *(const float4*)&Bs[kk][c0];
            *(float4*)&b[4] = *(const float4*)&Bs[kk][c0 + 4];
#pragma unroll
            for (int i = 0; i < 8; ++i)
#pragma unroll
                for (int j = 0; j < 8; ++j)
                    acc[i][j] = fmaf(a[i], b[j], acc[i][j]);
        }
        __syncthreads();
    }
#pragma unroll
    for (int i = 0; i < 8; ++i) {
        float* cp = C + (size_t)(bm + r0 + i) * HID + bn + c0;
        *(float4*)cp       = make_float4(acc[i][0], acc[i][1], acc[i][2], acc[i][3]);
        *(float4*)(cp + 4) = make_float4(acc[i][4], acc[i][5], acc[i][6], acc[i][7]);
    }
}

// ---------------------------------------------------------------------------
// Persistent ALIF scan: one block per batch element, one thread per neuron.
// Recurrent input = sum of WhhT columns listed in the compacted spike list
// (deterministic, sorted order). Readout via fixed-order partial reduction.
// ---------------------------------------------------------------------------
__global__ __launch_bounds__(1024)
void alif_scan(const float* __restrict__ CUR, const float* __restrict__ WhhT,
               const float* __restrict__ Wo,
               const float* __restrict__ tau_mem, const float* __restrict__ tau_adp,
               const float* __restrict__ tau_out,
               float* __restrict__ outputs,
               float* __restrict__ zS, float* __restrict__ uS, float* __restrict__ aS,
               float* __restrict__ ouS, float* __restrict__ spkS,
               int t0, int tc) {
    const int b    = blockIdx.x;
    const int h    = threadIdx.x;
    const int wid  = h >> 6;
    const int lane = h & 63;

    __shared__ int   s_list[HID];
    __shared__ int   s_wc[16];
    __shared__ int   s_cnt;
    __shared__ int   s_spk;
    __shared__ float s_ou[OUT_DIM];
    __shared__ float s_ao[OUT_DIM];
    __shared__ float s_part[OUT_DIM][16];

    float z = zS[(size_t)b * HID + h];
    float u = uS[(size_t)b * HID + h];
    float a = aS[(size_t)b * HID + h];
    const float alpha = expf(-1.f / tau_mem[h]);
    const float rho   = expf(-1.f / tau_adp[h]);
    const float oma   = 1.f - alpha;
    const float omr   = 1.f - rho;
    if (h < OUT_DIM) {
        s_ou[h] = ouS[(size_t)b * OUT_DIM + h];
        s_ao[h] = expf(-1.f / tau_out[h]);
    }
    if (h == 0) s_spk = 0;

    // initial compaction of carried-in z
    {
        unsigned long long m = __ballot(z > 0.5f);
        if (lane == 0) s_wc[wid] = __popcll(m);
        __syncthreads();
        int off = 0;
        for (int w = 0; w < wid; ++w) off += s_wc[w];
        if (z > 0.5f) s_list[off + __popcll(m & ((1ull << lane) - 1))] = h;
        if (h == 0) {
            int c = 0;
            for (int w = 0; w < 16; ++w) c += s_wc[w];
            s_cnt = c;
        }
        __syncthreads();
    }

    int wspk = 0;
    for (int tt = 0; tt < tc; ++tt) {
        const int n = s_cnt;
        const float xc = CUR[((size_t)tt * BATCH + b) * HID + h];
        float rec = 0.f;
        int i = 0;
        for (; i + 8 <= n; i += 8) {
            const int j0 = s_list[i + 0], j1 = s_list[i + 1];
            const int j2 = s_list[i + 2], j3 = s_list[i + 3];
            const int j4 = s_list[i + 4], j5 = s_list[i + 5];
            const int j6 = s_list[i + 6], j7 = s_list[i + 7];
            const float w0 = WhhT[(size_t)j0 * HID + h];
            const float w1 = WhhT[(size_t)j1 * HID + h];
            const float w2 = WhhT[(size_t)j2 * HID + h];
            const float w3 = WhhT[(size_t)j3 * HID + h];
            const float w4 = WhhT[(size_t)j4 * HID + h];
            const float w5 = WhhT[(size_t)j5 * HID + h];
            const float w6 = WhhT[(size_t)j6 * HID + h];
            const float w7 = WhhT[(size_t)j7 * HID + h];
            rec += w0; rec += w1; rec += w2; rec += w3;
            rec += w4; rec += w5; rec += w6; rec += w7;
        }
        for (; i < n; ++i) rec += WhhT[(size_t)s_list[i] * HID + h];

        a = rho * a + omr * z;
        const float theta = 0.01f + 1.8f * a;
        u = alpha * u + oma * (xc + rec) - z * theta;
        const float zn = (u - theta > 0.f) ? 1.f : 0.f;

        unsigned long long mm = __ballot(zn > 0.5f);
        if (lane == 0) {
            s_wc[wid] = __popcll(mm);
            wspk += __popcll(mm);
        }
        __syncthreads();                       // (A) rec reads done; s_wc ready
        {
            int off = 0;
            for (int w = 0; w < wid; ++w) off += s_wc[w];
            if (zn > 0.5f) s_list[off + __popcll(mm & ((1ull << lane) - 1))] = h;
            if (h == 0) {
                int c = 0;
                for (int w = 0; w < 16; ++w) c += s_wc[w];
                s_cnt = c;
            }
        }
        z = zn;
        __syncthreads();                       // (B) new list/cnt visible
        if (h < OUT_DIM * 16) {
            const int o = h >> 4, cc = h & 15;
            const int nn = s_cnt;
            float p = 0.f;
            for (int k2 = cc; k2 < nn; k2 += 16)
                p += Wo[(size_t)o * HID + s_list[k2]];
            s_part[o][cc] = p;
        }
        __syncthreads();                       // (C) partials visible
        if (h < OUT_DIM) {
            float s = 0.f;
#pragma unroll
            for (int cc = 0; cc < 16; ++cc) s += s_part[h][cc];
            const float ao  = s_ao[h];
            const float nou = ao * s_ou[h] + (1.f - ao) * s;
            s_ou[h] = nou;
            outputs[((size_t)(t0 + tt) * BATCH + b) * OUT_DIM + h] = nou;
        }
    }

    zS[(size_t)b * HID + h] = z;
    uS[(size_t)b * HID + h] = u;
    aS[(size_t)b * HID + h] = a;
    if (h < OUT_DIM) ouS[(size_t)b * OUT_DIM + h] = s_ou[h];
    if (lane == 0 && wspk) atomicAdd(&s_spk, wspk);
    __syncthreads();
    if (h == 0 && s_spk) atomicAdd(spkS, (float)s_spk);
}

// ---------------------------------------------------------------------------
extern "C" void kernel_launch(void* const* d_in, const int* in_sizes, int n_in,
                              void* d_out, int out_size, void* d_ws, size_t ws_size,
                              hipStream_t stream) {
    (void)in_sizes; (void)n_in; (void)out_size;
    const float* x       = (const float*)d_in[0];
    const float* W_h     = (const float*)d_in[1];
    const float* tau_mem = (const float*)d_in[2];
    const float* tau_adp = (const float*)d_in[3];
    const float* W_o     = (const float*)d_in[4];
    const float* tau_out = (const float*)d_in[5];

    float* out     = (float*)d_out;
    float* outputs = out;                                      // [250][256][20]
    float* zS  = out + (size_t)T_STEPS * BATCH * OUT_DIM;      // [256][1024]
    float* uS  = zS + (size_t)BATCH * HID;
    float* aS  = uS + (size_t)BATCH * HID;
    float* ouS = aS + (size_t)BATCH * HID;                     // [256][20]
    float* spk = ouS + (size_t)BATCH * OUT_DIM;                // scalar

    float* WhhT = (float*)d_ws;                                // 4 MB
    float* CUR  = WhhT + (size_t)HID * HID;

    const size_t whht_bytes = (size_t)HID * HID * sizeof(float);
    size_t cur_bytes = ws_size > whht_bytes ? ws_size - whht_bytes : 0;
    int CT = (int)(cur_bytes / ((size_t)BATCH * HID * sizeof(float)));
    if (CT > T_STEPS) CT = T_STEPS;
    if (CT < 1) CT = 1;

    // zero state + spike counter (zS..spk are contiguous in d_out)
    hipMemsetAsync(zS, 0,
                   ((size_t)3 * BATCH * HID + BATCH * OUT_DIM + 1) * sizeof(float),
                   stream);
    transpose_whh<<<dim3(32, 32), dim3(32, 8), 0, stream>>>(W_h, WhhT);

    for (int t0 = 0; t0 < T_STEPS; t0 += CT) {
        const int tc = (T_STEPS - t0 < CT) ? (T_STEPS - t0) : CT;
        input_gemm<<<dim3(tc * 2, HID / BN), 256, 0, stream>>>(
            x + (size_t)t0 * BATCH * IN_DIM, W_h, CUR, tc * BATCH);
        alif_scan<<<BATCH, HID, 0, stream>>>(CUR, WhhT, W_o,
                                             tau_mem, tau_adp, tau_out,
                                             outputs, zS, uS, aS, ouS, spk,
                                             t0, tc);
    }
}

// Round 2
// 1985.863 us; speedup vs baseline: 1.2344x; 1.2344x over previous
//
#include <hip/hip_runtime.h>

#define T_STEPS 250
#define BATCH   256
#define IN_DIM  700
#define HID     1024
#define W_LD    1724   // = IN_DIM + HID
#define OUT_DIM 20
#define KP      704    // K padded to 44*16 (700 = 175*4, so last float4 is pad)
#define KP4     (KP / 4)

// ---------------------------------------------------------------------------
// Transpose recurrent weights: WhhT[j][h] = W_h[h][700 + j]
// ---------------------------------------------------------------------------
__global__ __launch_bounds__(256)
void transpose_whh(const float* __restrict__ W_h, float* __restrict__ WhhT) {
    __shared__ float tile[32][33];
    const int bx = blockIdx.x * 32;  // h base
    const int by = blockIdx.y * 32;  // j base
    const int tx = threadIdx.x, ty = threadIdx.y;
#pragma unroll
    for (int i = 0; i < 32; i += 8) {
        const int h = bx + ty + i;
        const int j = by + tx;
        tile[ty + i][tx] = W_h[(size_t)h * W_LD + IN_DIM + j];
    }
    __syncthreads();
#pragma unroll
    for (int i = 0; i < 32; i += 8) {
        const int j = by + ty + i;
        const int h = bx + tx;
        WhhT[(size_t)j * HID + h] = tile[tx][ty + i];
    }
}

// ---------------------------------------------------------------------------
// Pack input rows into zero-padded stride-704 buffer (aligned float4 copies).
// ---------------------------------------------------------------------------
__global__ __launch_bounds__(256)
void pack_x(const float* __restrict__ x, float* __restrict__ Xp, int rows) {
    const int total = rows * KP4;
    for (int idx = blockIdx.x * blockDim.x + threadIdx.x; idx < total;
         idx += gridDim.x * blockDim.x) {
        const int r = idx / KP4;
        const int c = idx - r * KP4;
        float4 v = make_float4(0.f, 0.f, 0.f, 0.f);
        if (c < IN_DIM / 4) v = *(const float4*)(x + (size_t)r * IN_DIM + c * 4);
        ((float4*)Xp)[(size_t)r * KP4 + c] = v;
    }
}

// Pack W_h's first 700 columns (ld 1724) into stride-704 buffer.
__global__ __launch_bounds__(256)
void pack_w(const float* __restrict__ W_h, float* __restrict__ Wp) {
    const int total = HID * KP4;
    for (int idx = blockIdx.x * blockDim.x + threadIdx.x; idx < total;
         idx += gridDim.x * blockDim.x) {
        const int r = idx / KP4;
        const int c = idx - r * KP4;
        float4 v = make_float4(0.f, 0.f, 0.f, 0.f);
        if (c < IN_DIM / 4) v = *(const float4*)(W_h + (size_t)r * W_LD + c * 4);
        ((float4*)Wp)[(size_t)r * KP4 + c] = v;
    }
}

// ---------------------------------------------------------------------------
// Input-current GEMM: C[m][n] = sum_k Xp[m][k] * Wp[n][k], K = 704 branch-free.
// 128x128 tile, 256 threads, per-thread 8x8 as 2x2 blocks of 4x4 (stride-4
// float4 fragments -> <=2-way LDS bank aliasing, which is free on CDNA4).
// ---------------------------------------------------------------------------
#define LDP 132   // 128 + 4 pad

__global__ __launch_bounds__(256)
void input_gemm(const float* __restrict__ Xp, const float* __restrict__ Wp,
                float* __restrict__ C) {
    __shared__ float As[16][LDP];
    __shared__ float Bs[16][LDP];
    const int tid = threadIdx.x;
    const int bm = blockIdx.x * 128;
    const int bn = blockIdx.y * 128;
    const int r0 = (tid >> 4) * 4;   // 0..60
    const int c0 = (tid & 15) * 4;   // 0..60

    const int row_s = tid >> 2;        // staging row 0..63 (+64 for second)
    const int kq    = (tid & 3) * 4;   // staging k sub-column (floats)

    float4 aReg[2], bReg[2];

    auto stage = [&](int k0) {
        const float* pa = Xp + (size_t)(bm + row_s) * KP + k0 + kq;
        aReg[0] = *(const float4*)pa;
        aReg[1] = *(const float4*)(pa + (size_t)64 * KP);
        const float* pb = Wp + (size_t)(bn + row_s) * KP + k0 + kq;
        bReg[0] = *(const float4*)pb;
        bReg[1] = *(const float4*)(pb + (size_t)64 * KP);
    };
    auto commit = [&]() {
#pragma unroll
        for (int r = 0; r < 2; ++r) {
            const int row = row_s + r * 64;
            As[kq + 0][row] = aReg[r].x;
            As[kq + 1][row] = aReg[r].y;
            As[kq + 2][row] = aReg[r].z;
            As[kq + 3][row] = aReg[r].w;
            Bs[kq + 0][row] = bReg[r].x;
            Bs[kq + 1][row] = bReg[r].y;
            Bs[kq + 2][row] = bReg[r].z;
            Bs[kq + 3][row] = bReg[r].w;
        }
    };

    float acc[2][2][4][4];
#pragma unroll
    for (int p = 0; p < 2; ++p)
#pragma unroll
        for (int q = 0; q < 2; ++q)
#pragma unroll
            for (int i = 0; i < 4; ++i)
#pragma unroll
                for (int j = 0; j < 4; ++j) acc[p][q][i][j] = 0.f;

    const int nk = KP / 16;  // 44
    stage(0);
    for (int kt = 0; kt < nk; ++kt) {
        commit();
        __syncthreads();
        if (kt + 1 < nk) stage((kt + 1) * 16);
#pragma unroll
        for (int kk = 0; kk < 16; ++kk) {
            float a0[4], a1[4], b0[4], b1[4];
            *(float4*)a0 = *(const float4*)&As[kk][r0];
            *(float4*)a1 = *(const float4*)&As[kk][r0 + 64];
            *(float4*)b0 = *(const float4*)&Bs[kk][c0];
            *(float4*)b1 = *(const float4*)&Bs[kk][c0 + 64];
#pragma unroll
            for (int i = 0; i < 4; ++i)
#pragma unroll
                for (int j = 0; j < 4; ++j) {
                    acc[0][0][i][j] = fmaf(a0[i], b0[j], acc[0][0][i][j]);
                    acc[0][1][i][j] = fmaf(a0[i], b1[j], acc[0][1][i][j]);
                    acc[1][0][i][j] = fmaf(a1[i], b0[j], acc[1][0][i][j]);
                    acc[1][1][i][j] = fmaf(a1[i], b1[j], acc[1][1][i][j]);
                }
        }
        __syncthreads();
    }
#pragma unroll
    for (int ri = 0; ri < 2; ++ri)
#pragma unroll
        for (int i = 0; i < 4; ++i) {
            float* cp = C + (size_t)(bm + ri * 64 + r0 + i) * HID + bn;
            *(float4*)(cp + c0) =
                make_float4(acc[ri][0][i][0], acc[ri][0][i][1],
                            acc[ri][0][i][2], acc[ri][0][i][3]);
            *(float4*)(cp + 64 + c0) =
                make_float4(acc[ri][1][i][0], acc[ri][1][i][1],
                            acc[ri][1][i][2], acc[ri][1][i][3]);
        }
}

// ---------------------------------------------------------------------------
// Persistent ALIF scan: one block per batch element, one thread per neuron.
// ---------------------------------------------------------------------------
__global__ __launch_bounds__(1024)
void alif_scan(const float* __restrict__ CUR, const float* __restrict__ WhhT,
               const float* __restrict__ Wo,
               const float* __restrict__ tau_mem, const float* __restrict__ tau_adp,
               const float* __restrict__ tau_out,
               float* __restrict__ outputs,
               float* __restrict__ zS, float* __restrict__ uS, float* __restrict__ aS,
               float* __restrict__ ouS, float* __restrict__ spkS,
               int t0, int tc) {
    const int b    = blockIdx.x;
    const int h    = threadIdx.x;
    const int wid  = h >> 6;
    const int lane = h & 63;

    __shared__ int   s_list[HID];
    __shared__ int   s_wc[16];
    __shared__ int   s_cnt;
    __shared__ int   s_spk;
    __shared__ float s_ou[OUT_DIM];
    __shared__ float s_ao[OUT_DIM];
    __shared__ float s_part[OUT_DIM][16];

    float z = zS[(size_t)b * HID + h];
    float u = uS[(size_t)b * HID + h];
    float a = aS[(size_t)b * HID + h];
    const float alpha = expf(-1.f / tau_mem[h]);
    const float rho   = expf(-1.f / tau_adp[h]);
    const float oma   = 1.f - alpha;
    const float omr   = 1.f - rho;
    if (h < OUT_DIM) {
        s_ou[h] = ouS[(size_t)b * OUT_DIM + h];
        s_ao[h] = expf(-1.f / tau_out[h]);
    }
    if (h == 0) s_spk = 0;

    {
        unsigned long long m = __ballot(z > 0.5f);
        if (lane == 0) s_wc[wid] = __popcll(m);
        __syncthreads();
        int off = 0;
        for (int w = 0; w < wid; ++w) off += s_wc[w];
        if (z > 0.5f) s_list[off + __popcll(m & ((1ull << lane) - 1))] = h;
        if (h == 0) {
            int c = 0;
            for (int w = 0; w < 16; ++w) c += s_wc[w];
            s_cnt = c;
        }
        __syncthreads();
    }

    int wspk = 0;
    for (int tt = 0; tt < tc; ++tt) {
        const int n = s_cnt;
        const float xc = CUR[((size_t)tt * BATCH + b) * HID + h];
        float rec = 0.f;
        int i = 0;
        for (; i + 8 <= n; i += 8) {
            const int j0 = s_list[i + 0], j1 = s_list[i + 1];
            const int j2 = s_list[i + 2], j3 = s_list[i + 3];
            const int j4 = s_list[i + 4], j5 = s_list[i + 5];
            const int j6 = s_list[i + 6], j7 = s_list[i + 7];
            const float w0 = WhhT[(size_t)j0 * HID + h];
            const float w1 = WhhT[(size_t)j1 * HID + h];
            const float w2 = WhhT[(size_t)j2 * HID + h];
            const float w3 = WhhT[(size_t)j3 * HID + h];
            const float w4 = WhhT[(size_t)j4 * HID + h];
            const float w5 = WhhT[(size_t)j5 * HID + h];
            const float w6 = WhhT[(size_t)j6 * HID + h];
            const float w7 = WhhT[(size_t)j7 * HID + h];
            rec += w0; rec += w1; rec += w2; rec += w3;
            rec += w4; rec += w5; rec += w6; rec += w7;
        }
        for (; i < n; ++i) rec += WhhT[(size_t)s_list[i] * HID + h];

        a = rho * a + omr * z;
        const float theta = 0.01f + 1.8f * a;
        u = alpha * u + oma * (xc + rec) - z * theta;
        const float zn = (u - theta > 0.f) ? 1.f : 0.f;

        unsigned long long mm = __ballot(zn > 0.5f);
        if (lane == 0) {
            s_wc[wid] = __popcll(mm);
            wspk += __popcll(mm);
        }
        __syncthreads();                       // (A)
        {
            int off = 0;
            for (int w = 0; w < wid; ++w) off += s_wc[w];
            if (zn > 0.5f) s_list[off + __popcll(mm & ((1ull << lane) - 1))] = h;
            if (h == 0) {
                int c = 0;
                for (int w = 0; w < 16; ++w) c += s_wc[w];
                s_cnt = c;
            }
        }
        z = zn;
        __syncthreads();                       // (B)
        if (h < OUT_DIM * 16) {
            const int o = h >> 4, cc = h & 15;
            const int nn = s_cnt;
            float p = 0.f;
            for (int k2 = cc; k2 < nn; k2 += 16)
                p += Wo[(size_t)o * HID + s_list[k2]];
            s_part[o][cc] = p;
        }
        __syncthreads();                       // (C)
        if (h < OUT_DIM) {
            float s = 0.f;
#pragma unroll
            for (int cc = 0; cc < 16; ++cc) s += s_part[h][cc];
            const float ao  = s_ao[h];
            const float nou = ao * s_ou[h] + (1.f - ao) * s;
            s_ou[h] = nou;
            outputs[((size_t)(t0 + tt) * BATCH + b) * OUT_DIM + h] = nou;
        }
    }

    zS[(size_t)b * HID + h] = z;
    uS[(size_t)b * HID + h] = u;
    aS[(size_t)b * HID + h] = a;
    if (h < OUT_DIM) ouS[(size_t)b * OUT_DIM + h] = s_ou[h];
    if (lane == 0 && wspk) atomicAdd(&s_spk, wspk);
    __syncthreads();
    if (h == 0 && s_spk) atomicAdd(spkS, (float)s_spk);
}

// ---------------------------------------------------------------------------
extern "C" void kernel_launch(void* const* d_in, const int* in_sizes, int n_in,
                              void* d_out, int out_size, void* d_ws, size_t ws_size,
                              hipStream_t stream) {
    (void)in_sizes; (void)n_in; (void)out_size;
    const float* x       = (const float*)d_in[0];
    const float* W_h     = (const float*)d_in[1];
    const float* tau_mem = (const float*)d_in[2];
    const float* tau_adp = (const float*)d_in[3];
    const float* W_o     = (const float*)d_in[4];
    const float* tau_out = (const float*)d_in[5];

    float* out     = (float*)d_out;
    float* outputs = out;                                      // [250][256][20]
    float* zS  = out + (size_t)T_STEPS * BATCH * OUT_DIM;      // [256][1024]
    float* uS  = zS + (size_t)BATCH * HID;
    float* aS  = uS + (size_t)BATCH * HID;
    float* ouS = aS + (size_t)BATCH * HID;                     // [256][20]
    float* spk = ouS + (size_t)BATCH * OUT_DIM;                // scalar

    // ws layout: WhhT [1024*1024] | Wp [1024*704] | per-chunk { Xp | CUR }
    float* WhhT = (float*)d_ws;
    float* Wp   = WhhT + (size_t)HID * HID;
    float* dynb = Wp + (size_t)HID * KP;

    const size_t fixed_floats = (size_t)HID * HID + (size_t)HID * KP;
    const size_t avail = ws_size / sizeof(float) > fixed_floats
                       ? ws_size / sizeof(float) - fixed_floats : 0;
    const size_t per_step = (size_t)BATCH * KP + (size_t)BATCH * HID;
    int CT = (int)(avail / per_step);
    if (CT > T_STEPS) CT = T_STEPS;
    if (CT < 1) CT = 1;

    hipMemsetAsync(zS, 0,
                   ((size_t)3 * BATCH * HID + BATCH * OUT_DIM + 1) * sizeof(float),
                   stream);
    transpose_whh<<<dim3(32, 32), dim3(32, 8), 0, stream>>>(W_h, WhhT);
    pack_w<<<512, 256, 0, stream>>>(W_h, Wp);

    for (int t0 = 0; t0 < T_STEPS; t0 += CT) {
        const int tc = (T_STEPS - t0 < CT) ? (T_STEPS - t0) : CT;
        float* Xp  = dynb;
        float* CUR = dynb + (size_t)tc * BATCH * KP;
        const int rows = tc * BATCH;
        int pblocks = (rows * KP4 + 255) / 256;
        if (pblocks > 2048) pblocks = 2048;
        pack_x<<<pblocks, 256, 0, stream>>>(x + (size_t)t0 * BATCH * IN_DIM, Xp, rows);
        input_gemm<<<dim3(rows / 128, HID / 128), 256, 0, stream>>>(Xp, Wp, CUR);
        alif_scan<<<BATCH, HID, 0, stream>>>(CUR, WhhT, W_o,
                                             tau_mem, tau_adp, tau_out,
                                             outputs, zS, uS, aS, ouS, spk,
                                             t0, tc);
    }
}

// Round 3
// 1271.397 us; speedup vs baseline: 1.9281x; 1.5620x over previous
//
#include <hip/hip_runtime.h>

#define T_STEPS 250
#define BATCH   256
#define IN_DIM  700
#define HID     1024
#define W_LD    1724   // = IN_DIM + HID
#define OUT_DIM 20
#define KP      704    // K padded to 22*32
#define KP4     (KP / 4)
#define NKT     (KP / 32)

typedef __attribute__((ext_vector_type(8))) short     bf16x8;
typedef __attribute__((ext_vector_type(8))) unsigned short u16x8;
typedef __attribute__((ext_vector_type(4))) float     f32x4;
typedef unsigned long long u64;

__device__ inline unsigned short f2bf(float f) {
    unsigned int u = __float_as_uint(f);
    unsigned int r = u + 0x7FFFu + ((u >> 16) & 1u);
    return (unsigned short)(r >> 16);
}
__device__ inline float bf2f(unsigned short w) {
    return __uint_as_float(((unsigned int)w) << 16);
}

// ---------------------------------------------------------------------------
// WhhT_bf16[j][h] = bf16(W_h[h][700 + j])
// ---------------------------------------------------------------------------
__global__ __launch_bounds__(256)
void trans_whh_bf16(const float* __restrict__ W_h, unsigned short* __restrict__ WhhT) {
    __shared__ float tile[32][33];
    const int bx = blockIdx.x * 32;  // h base
    const int by = blockIdx.y * 32;  // j base
    const int tx = threadIdx.x, ty = threadIdx.y;
#pragma unroll
    for (int i = 0; i < 32; i += 8)
        tile[ty + i][tx] = W_h[(size_t)(bx + ty + i) * W_LD + IN_DIM + by + tx];
    __syncthreads();
#pragma unroll
    for (int i = 0; i < 32; i += 8)
        WhhT[(size_t)(by + ty + i) * HID + bx + tx] = f2bf(tile[tx][ty + i]);
}

// WoT[h][o] = Wo[o][h]
__global__ __launch_bounds__(256)
void trans_wo(const float* __restrict__ Wo, float* __restrict__ WoT) {
    const int h = blockIdx.x * 256 + threadIdx.x;
    if (h >= HID) return;
#pragma unroll
    for (int o = 0; o < OUT_DIM; ++o)
        WoT[(size_t)h * OUT_DIM + o] = Wo[(size_t)o * HID + h];
}

// ---------------------------------------------------------------------------
// Pack x rows -> zero-padded K=704 bf16
// ---------------------------------------------------------------------------
__global__ __launch_bounds__(256)
void pack_x_bf16(const float* __restrict__ x, unsigned short* __restrict__ Xp, int rows) {
    const int total = rows * KP4;
    for (int idx = blockIdx.x * blockDim.x + threadIdx.x; idx < total;
         idx += gridDim.x * blockDim.x) {
        const int r = idx / KP4;
        const int c = idx - r * KP4;
        ushort4 o = make_ushort4(0, 0, 0, 0);
        if (c < IN_DIM / 4) {
            float4 v = *(const float4*)(x + (size_t)r * IN_DIM + c * 4);
            o = make_ushort4(f2bf(v.x), f2bf(v.y), f2bf(v.z), f2bf(v.w));
        }
        ((ushort4*)Xp)[(size_t)r * KP4 + c] = o;
    }
}

// Pack W_h's first 700 cols (ld 1724) -> [1024][704] bf16
__global__ __launch_bounds__(256)
void pack_w_bf16(const float* __restrict__ W_h, unsigned short* __restrict__ Wp) {
    const int total = HID * KP4;
    for (int idx = blockIdx.x * blockDim.x + threadIdx.x; idx < total;
         idx += gridDim.x * blockDim.x) {
        const int r = idx / KP4;
        const int c = idx - r * KP4;
        ushort4 o = make_ushort4(0, 0, 0, 0);
        if (c < IN_DIM / 4) {
            float4 v = *(const float4*)(W_h + (size_t)r * W_LD + c * 4);
            o = make_ushort4(f2bf(v.x), f2bf(v.y), f2bf(v.z), f2bf(v.w));
        }
        ((ushort4*)Wp)[(size_t)r * KP4 + c] = o;
    }
}

// ---------------------------------------------------------------------------
// bf16 MFMA GEMM: C[m][n] = sum_k A[m][k]*B[n][k]; A [M][704], B [1024][704].
// 128x128 tile, BK=32, 4 waves (2x2), each wave 64x64 = 4x4 16x16x32 frags.
// LDS XOR-swizzled (byte ^= (row&7)<<4) on write and read: conflict-optimal.
// ---------------------------------------------------------------------------
__global__ __launch_bounds__(256)
void mfma_gemm(const unsigned short* __restrict__ A,
               const unsigned short* __restrict__ B, float* __restrict__ C) {
    __shared__ unsigned short lA[128 * 32];
    __shared__ unsigned short lB[128 * 32];
    const int tid  = threadIdx.x;
    const int wid  = tid >> 6, lane = tid & 63;
    const int wr   = wid >> 1, wc = wid & 1;
    const size_t bm = (size_t)blockIdx.x * 128;
    const size_t bn = (size_t)blockIdx.y * 128;

    const int srow = tid >> 2;         // staging rows srow, srow+64
    const int skq  = (tid & 3) * 8;    // staging k offset (elems)

    const int wb0 = (srow * 64 + (tid & 3) * 16) ^ ((srow & 7) << 4);
    const int wb1 = ((srow + 64) * 64 + (tid & 3) * 16) ^ ((srow & 7) << 4);

    const unsigned short* pa = A + (bm + srow) * KP + skq;
    const unsigned short* pb = B + (bn + srow) * KP + skq;

    u16x8 ra0, ra1, rb0, rb1;
    auto ldg = [&](int k0) {
        ra0 = *(const u16x8*)(pa + k0);
        ra1 = *(const u16x8*)(pa + (size_t)64 * KP + k0);
        rb0 = *(const u16x8*)(pb + k0);
        rb1 = *(const u16x8*)(pb + (size_t)64 * KP + k0);
    };

    const int arow = wr * 64 + (lane & 15);
    const int brow = wc * 64 + (lane & 15);
    const int fq   = (lane >> 4) * 16;  // byte offset in row

    f32x4 acc[4][4];
#pragma unroll
    for (int m = 0; m < 4; ++m)
#pragma unroll
        for (int n = 0; n < 4; ++n) acc[m][n] = (f32x4){0.f, 0.f, 0.f, 0.f};

    ldg(0);
    for (int kt = 0; kt < NKT; ++kt) {
        *(u16x8*)((char*)lA + wb0) = ra0;
        *(u16x8*)((char*)lA + wb1) = ra1;
        *(u16x8*)((char*)lB + wb0) = rb0;
        *(u16x8*)((char*)lB + wb1) = rb1;
        __syncthreads();
        if (kt + 1 < NKT) ldg((kt + 1) * 32);
        bf16x8 af[4], bf[4];
#pragma unroll
        for (int m = 0; m < 4; ++m) {
            const int row = arow + m * 16;
            af[m] = *(const bf16x8*)((const char*)lA + ((row * 64 + fq) ^ ((row & 7) << 4)));
        }
#pragma unroll
        for (int n = 0; n < 4; ++n) {
            const int row = brow + n * 16;
            bf[n] = *(const bf16x8*)((const char*)lB + ((row * 64 + fq) ^ ((row & 7) << 4)));
        }
#pragma unroll
        for (int m = 0; m < 4; ++m)
#pragma unroll
            for (int n = 0; n < 4; ++n)
                acc[m][n] = __builtin_amdgcn_mfma_f32_16x16x32_bf16(af[m], bf[n], acc[m][n], 0, 0, 0);
        __syncthreads();
    }
    // C/D layout: col = lane&15, row = (lane>>4)*4 + r  (m89-verified)
#pragma unroll
    for (int m = 0; m < 4; ++m)
#pragma unroll
        for (int r = 0; r < 4; ++r) {
            float* cp = C + (bm + wr * 64 + m * 16 + (lane >> 4) * 4 + r) * HID
                          + bn + wc * 64 + (lane & 15);
#pragma unroll
            for (int n = 0; n < 4; ++n) cp[n * 16] = acc[m][n][r];
        }
}

// ---------------------------------------------------------------------------
// Persistent ALIF scan: 1 block/batch, 1 thread/neuron. bf16 recurrent
// weights, 2 barriers/step, readout deferred via per-wave spike bitmasks.
// ---------------------------------------------------------------------------
__global__ __launch_bounds__(1024)
void alif_scan(const float* __restrict__ CUR, const unsigned short* __restrict__ WhhT,
               const float* __restrict__ tau_mem, const float* __restrict__ tau_adp,
               float* __restrict__ zS, float* __restrict__ uS, float* __restrict__ aS,
               float* __restrict__ spkS, u64* __restrict__ masks,
               int t0, int tc) {
    const int b    = blockIdx.x;
    const int h    = threadIdx.x;
    const int wid  = h >> 6;
    const int lane = h & 63;

    __shared__ int s_list[HID];
    __shared__ int s_wc[16];
    __shared__ int s_cnt;
    __shared__ int s_spk;

    float z = zS[(size_t)b * HID + h];
    float u = uS[(size_t)b * HID + h];
    float a = aS[(size_t)b * HID + h];
    const float alpha = expf(-1.f / tau_mem[h]);
    const float rho   = expf(-1.f / tau_adp[h]);
    const float oma   = 1.f - alpha;
    const float omr   = 1.f - rho;
    if (h == 0) s_spk = 0;

    {   // initial compaction of carried-in z
        unsigned long long m = __ballot(z > 0.5f);
        if (lane == 0) s_wc[wid] = __popcll(m);
        __syncthreads();
        int off = 0;
        for (int w = 0; w < wid; ++w) off += s_wc[w];
        if (z > 0.5f) s_list[off + __popcll(m & ((1ull << lane) - 1))] = h;
        if (h == 0) {
            int c = 0;
            for (int w = 0; w < 16; ++w) c += s_wc[w];
            s_cnt = c;
        }
        __syncthreads();
    }

    const unsigned short* Wb = WhhT + h;
    int wspk = 0;
    for (int tt = 0; tt < tc; ++tt) {
        const int n = s_cnt;
        const float xc = CUR[((size_t)tt * BATCH + b) * HID + h];
        float rec = 0.f;
        int i = 0;
        for (; i + 8 <= n; i += 8) {
            const int j0 = s_list[i + 0], j1 = s_list[i + 1];
            const int j2 = s_list[i + 2], j3 = s_list[i + 3];
            const int j4 = s_list[i + 4], j5 = s_list[i + 5];
            const int j6 = s_list[i + 6], j7 = s_list[i + 7];
            const float w0 = bf2f(Wb[(size_t)j0 << 10]);
            const float w1 = bf2f(Wb[(size_t)j1 << 10]);
            const float w2 = bf2f(Wb[(size_t)j2 << 10]);
            const float w3 = bf2f(Wb[(size_t)j3 << 10]);
            const float w4 = bf2f(Wb[(size_t)j4 << 10]);
            const float w5 = bf2f(Wb[(size_t)j5 << 10]);
            const float w6 = bf2f(Wb[(size_t)j6 << 10]);
            const float w7 = bf2f(Wb[(size_t)j7 << 10]);
            rec += w0; rec += w1; rec += w2; rec += w3;
            rec += w4; rec += w5; rec += w6; rec += w7;
        }
        for (; i < n; ++i) rec += bf2f(Wb[(size_t)s_list[i] << 10]);

        a = rho * a + omr * z;
        const float theta = 0.01f + 1.8f * a;
        u = alpha * u + oma * (xc + rec) - z * theta;
        const float zn = (u - theta > 0.f) ? 1.f : 0.f;

        unsigned long long mm = __ballot(zn > 0.5f);
        if (lane == 0) {
            s_wc[wid] = __popcll(mm);
            wspk += __popcll(mm);
            masks[((size_t)(t0 + tt) * BATCH + b) * 16 + wid] = mm;
        }
        __syncthreads();                       // (A) rec reads done; s_wc ready
        {
            int off = 0;
            for (int w = 0; w < wid; ++w) off += s_wc[w];
            if (zn > 0.5f) s_list[off + __popcll(mm & ((1ull << lane) - 1))] = h;
            if (h == 0) {
                int c = 0;
                for (int w = 0; w < 16; ++w) c += s_wc[w];
                s_cnt = c;
            }
        }
        z = zn;
        __syncthreads();                       // (B) new list visible
    }

    zS[(size_t)b * HID + h] = z;
    uS[(size_t)b * HID + h] = u;
    aS[(size_t)b * HID + h] = a;
    if (lane == 0 && wspk) atomicAdd(&s_spk, wspk);
    __syncthreads();
    if (h == 0 && s_spk) atomicAdd(spkS, (float)s_spk);
}

// ---------------------------------------------------------------------------
// y[t*B+b][o] = sum over spiking j of WoT[j][o]  (one wave per (t,b) pair)
// ---------------------------------------------------------------------------
__global__ __launch_bounds__(256)
void readout_y(const u64* __restrict__ masks, const float* __restrict__ WoT,
               float* __restrict__ y, int npairs) {
    const int pr   = blockIdx.x * 4 + (threadIdx.x >> 6);
    const int lane = threadIdx.x & 63;
    if (pr >= npairs) return;
    const u64* mp = masks + (size_t)pr * 16;
    float acc = 0.f;
#pragma unroll 4
    for (int w = 0; w < 16; ++w) {
        u64 m = mp[w];
        while (m) {
            const int j = __ffsll((unsigned long long)m) - 1;
            m &= m - 1;
            if (lane < OUT_DIM) acc += WoT[(size_t)(w * 64 + j) * OUT_DIM + lane];
        }
    }
    if (lane < OUT_DIM) y[(size_t)pr * OUT_DIM + lane] = acc;
}

// ---------------------------------------------------------------------------
// outputs[t][b][o] = EWA over t of y; writes final ouT.
// ---------------------------------------------------------------------------
__global__ __launch_bounds__(256)
void ewa_out(const float* __restrict__ y, const float* __restrict__ tau_out,
             float* __restrict__ outputs, float* __restrict__ ouS) {
    const int idx = blockIdx.x * 256 + threadIdx.x;
    if (idx >= BATCH * OUT_DIM) return;
    const int o = idx % OUT_DIM;
    const float ao = expf(-1.f / tau_out[o]);
    float ou = ouS[idx];
    for (int t = 0; t < T_STEPS; ++t) {
        const float v = y[(size_t)t * BATCH * OUT_DIM + idx];
        ou = ao * ou + (1.f - ao) * v;
        outputs[(size_t)t * BATCH * OUT_DIM + idx] = ou;
    }
    ouS[idx] = ou;
}

// ---------------------------------------------------------------------------
extern "C" void kernel_launch(void* const* d_in, const int* in_sizes, int n_in,
                              void* d_out, int out_size, void* d_ws, size_t ws_size,
                              hipStream_t stream) {
    (void)in_sizes; (void)n_in; (void)out_size;
    const float* x       = (const float*)d_in[0];
    const float* W_h     = (const float*)d_in[1];
    const float* tau_mem = (const float*)d_in[2];
    const float* tau_adp = (const float*)d_in[3];
    const float* W_o     = (const float*)d_in[4];
    const float* tau_out = (const float*)d_in[5];

    float* out     = (float*)d_out;
    float* outputs = out;                                      // [250][256][20]
    float* zS  = out + (size_t)T_STEPS * BATCH * OUT_DIM;      // [256][1024]
    float* uS  = zS + (size_t)BATCH * HID;
    float* aS  = uS + (size_t)BATCH * HID;
    float* ouS = aS + (size_t)BATCH * HID;                     // [256][20]
    float* spk = ouS + (size_t)BATCH * OUT_DIM;                // scalar

    // ws layout (bytes)
    char* w = (char*)d_ws;
    unsigned short* WhhT = (unsigned short*)w; w += (size_t)HID * HID * 2;       // 2 MB
    unsigned short* Wp   = (unsigned short*)w; w += (size_t)HID * KP * 2;        // 1.4 MB
    float*          WoT  = (float*)w;          w += (size_t)HID * OUT_DIM * 4;   // 80 KB
    u64*            masks= (u64*)w;            w += (size_t)T_STEPS * BATCH * 16 * 8; // 8 MB
    float*          yBuf = (float*)w;          w += (size_t)T_STEPS * BATCH * OUT_DIM * 4; // 5 MB
    char*           dynb = w;

    const size_t fixed = (size_t)(dynb - (char*)d_ws);
    const size_t per_step = (size_t)BATCH * KP * 2 + (size_t)BATCH * HID * 4;
    const size_t avail = ws_size > fixed ? ws_size - fixed : 0;
    int CT = (int)(avail / per_step);
    if (CT > T_STEPS) CT = T_STEPS;
    if (CT < 1) CT = 1;

    hipMemsetAsync(zS, 0,
                   ((size_t)3 * BATCH * HID + BATCH * OUT_DIM + 1) * sizeof(float),
                   stream);
    trans_whh_bf16<<<dim3(32, 32), dim3(32, 8), 0, stream>>>(W_h, WhhT);
    pack_w_bf16<<<512, 256, 0, stream>>>(W_h, Wp);
    trans_wo<<<4, 256, 0, stream>>>(W_o, WoT);

    for (int t0 = 0; t0 < T_STEPS; t0 += CT) {
        const int tc = (T_STEPS - t0 < CT) ? (T_STEPS - t0) : CT;
        const int rows = tc * BATCH;
        unsigned short* Xp = (unsigned short*)dynb;
        float* CUR = (float*)(dynb + (size_t)rows * KP * 2);
        int pblocks = (rows * KP4 + 255) / 256;
        if (pblocks > 2048) pblocks = 2048;
        pack_x_bf16<<<pblocks, 256, 0, stream>>>(x + (size_t)t0 * BATCH * IN_DIM, Xp, rows);
        mfma_gemm<<<dim3(rows / 128, HID / 128), 256, 0, stream>>>(Xp, Wp, CUR);
        alif_scan<<<BATCH, HID, 0, stream>>>(CUR, WhhT, tau_mem, tau_adp,
                                             zS, uS, aS, spk, masks, t0, tc);
    }

    const int npairs = T_STEPS * BATCH;
    readout_y<<<(npairs + 3) / 4, 256, 0, stream>>>(masks, WoT, yBuf, npairs);
    ewa_out<<<(BATCH * OUT_DIM + 255) / 256, 256, 0, stream>>>(yBuf, tau_out, outputs, ouS);
}